// Round 3
// baseline (149.624 us; speedup 1.0000x reference)
//
#include <hip/hip_runtime.h>

// Problem constants (from reference):
//   x: (B=256, K=18, 2) int32 coords in [0,128)
//   out[b][h][w][k] = (|h - r| <= 5 && |w - c| <= 5) ? 1.0f : 0.0f
//   out shape (256, 128, 64, 18) fp32 -> 37,748,736 floats = 151 MB (write-bound)

constexpr int KP     = 18;   // keypoints
constexpr int AH     = 5;    // half patch height
constexpr int AW     = 5;    // half patch width

// Each block: 256 threads, 9216 consecutive floats = 512 pixels = 8 rows of one
// batch image. 16 blocks per batch, grid = 256*16 = 4096 blocks.
// Value of a pixel's k-th float = bit k of (rowmask[h] & colmask[w]).

__global__ __launch_bounds__(256) void posemap_kernel(const int* __restrict__ x,
                                                      float* __restrict__ out) {
    const int blk = blockIdx.x;
    const int b   = blk >> 4;           // 16 blocks per batch
    const int h0  = (blk & 15) << 3;    // first of 8 rows this block covers

    __shared__ unsigned rowmask[8];
    __shared__ unsigned colmask[64];

    const int t = threadIdx.x;
    const int* __restrict__ xb = x + b * (KP * 2);  // uniform per block -> s_loads

    if (t < 8) {
        const int h = h0 + t;
        unsigned m = 0;
        #pragma unroll
        for (int k = 0; k < KP; ++k) {
            const int r = xb[2 * k];
            m |= (unsigned)((unsigned)(h - r + AH) <= (unsigned)(2 * AH)) << k;
        }
        rowmask[t] = m;
    } else if (t >= 64 && t < 128) {
        const int w = t - 64;
        unsigned m = 0;
        #pragma unroll
        for (int k = 0; k < KP; ++k) {
            const int c = xb[2 * k + 1];
            m |= (unsigned)((unsigned)(w - c + AW) <= (unsigned)(2 * AW)) << k;
        }
        colmask[w] = m;
    }
    __syncthreads();

    float* __restrict__ obase = out + (size_t)blk * 9216;

    #pragma unroll
    for (int j = 0; j < 9; ++j) {
        const int q  = j * 256 + t;        // float4 index within block, 0..2303
        const int m  = q * 4;              // element offset within block, 0..9212
        const int pl = (int)((unsigned)m / 18u);   // local pixel 0..511 (mulhi magic)
        const int k0 = m - pl * 18;                // first k of this float4, 0..17

        // Masks for this pixel and the next (float4 may straddle a pixel).
        const int pl2 = (pl + 1) & 511;    // wrap only hit when unused (k0+3 < 18 at block end)
        const unsigned m1 = rowmask[pl  >> 6] & colmask[pl  & 63];
        const unsigned m2 = rowmask[pl2 >> 6] & colmask[pl2 & 63];
        const unsigned long long bits =
            (unsigned long long)m1 | ((unsigned long long)m2 << KP);

        float4 v;
        v.x = (float)((bits >> (k0 + 0)) & 1ull);
        v.y = (float)((bits >> (k0 + 1)) & 1ull);
        v.z = (float)((bits >> (k0 + 2)) & 1ull);
        v.w = (float)((bits >> (k0 + 3)) & 1ull);

        *reinterpret_cast<float4*>(obase + m) = v;   // coalesced: wave writes 1 KiB contiguous
    }
}

extern "C" void kernel_launch(void* const* d_in, const int* in_sizes, int n_in,
                              void* d_out, int out_size, void* d_ws, size_t ws_size,
                              hipStream_t stream) {
    const int* x = (const int*)d_in[0];
    float* out   = (float*)d_out;
    // 37,748,736 floats / 9216 per block = 4096 blocks
    posemap_kernel<<<4096, 256, 0, stream>>>(x, out);
}